// Round 1
// baseline (49500.598 us; speedup 1.0000x reference)
//
#include <hip/hip_runtime.h>
#include <math.h>

// Problem dims (fixed by reference)
#define NB     64      // batch
#define TT     512     // encoder timesteps
#define KS     256     // key size
#define VS     256     // value size
#define HID    512     // hidden (= KS+VS)
#define GATES  1024    // 4*KS
#define LL     256     // decoder steps
#define VOC    10000
#define SOSTOK 33

#define NBLK   256     // cooperative grid blocks (1 per CU)
#define GBLK   64      // blocks per super-group (16 batch rows)
#define NTHR   256

__device__ __forceinline__ float sigmoidf_(float x) { return 1.0f / (1.0f + expf(-x)); }

// ---------------------------------------------------------------------------
// Pack kernel: W1c[j][k] = row-contiguous [ctx | h1] weights of gate row j.
//   W1c[j][k] : k<256 -> W_ih1[j][512+k] (ctx part), k>=256 -> W_hh1[j][k-256]
//   W2c[j][k] : k<256 -> W_ih2[j][k]     (h1 part),  k>=256 -> W_hh2[j][k-256]
// Also sums biases and zeroes the sync counters/barriers.
// ---------------------------------------------------------------------------
__global__ __launch_bounds__(256)
void pack_kernel(const float* __restrict__ W_ih1, const float* __restrict__ W_hh1,
                 const float* __restrict__ b_ih1, const float* __restrict__ b_hh1,
                 const float* __restrict__ W_ih2, const float* __restrict__ W_hh2,
                 const float* __restrict__ b_ih2, const float* __restrict__ b_hh2,
                 float* __restrict__ W1c, float* __restrict__ W2c,
                 float* __restrict__ b1s, float* __restrict__ b2s,
                 unsigned* __restrict__ cnt, unsigned* __restrict__ bars)
{
    int idx = blockIdx.x * 256 + threadIdx.x;
    if (idx < 1024 * 512) {
        int j = idx >> 9;
        int k = idx & 511;
        W1c[idx] = (k < 256) ? W_ih1[j * 768 + 512 + k] : W_hh1[j * 256 + (k - 256)];
        W2c[idx] = (k < 256) ? W_ih2[j * 256 + k]       : W_hh2[j * 256 + (k - 256)];
    }
    if (idx < 1024) {
        b1s[idx] = b_ih1[idx] + b_hh1[idx];
        b2s[idx] = b_ih2[idx] + b_hh2[idx];
        cnt[idx] = 0u;
    }
    if (idx < 256) bars[idx] = 0u;
}

// ---------------------------------------------------------------------------
// Generic fp32 NT GEMM (unchanged from previous version).
// ---------------------------------------------------------------------------
template <int MODE>
__global__ __launch_bounds__(256)
void gemm_nt(const float* __restrict__ A, const float* __restrict__ B,
             float* __restrict__ C, const float* __restrict__ bias,
             int M, int Nn, int K, int lda, int ldb, int ldc)
{
    const int BM = 128, BN = 128, BK = 16;
    __shared__ float As[BK][BM + 4];
    __shared__ float Bs[BK][BN + 4];

    const int m0 = blockIdx.y * BM;
    const int n0 = blockIdx.x * BN;
    const int tid = threadIdx.x;
    const int tx = tid & 15;
    const int ty = tid >> 4;
    const int lr = tid >> 2;
    const int lq = tid & 3;

    float acc[8][8];
#pragma unroll
    for (int i = 0; i < 8; i++)
#pragma unroll
        for (int j = 0; j < 8; j++) acc[i][j] = 0.0f;

    for (int k0 = 0; k0 < K; k0 += BK) {
#pragma unroll
        for (int h = 0; h < 2; h++) {
            int r = lr + h * 64;
            int gm = m0 + r;
            float4 v = make_float4(0.f, 0.f, 0.f, 0.f);
            if (gm < M) v = *(const float4*)(A + (size_t)gm * lda + k0 + lq * 4);
            As[lq * 4 + 0][r] = v.x; As[lq * 4 + 1][r] = v.y;
            As[lq * 4 + 2][r] = v.z; As[lq * 4 + 3][r] = v.w;
        }
#pragma unroll
        for (int h = 0; h < 2; h++) {
            int r = lr + h * 64;
            int gn = n0 + r;
            float4 v = make_float4(0.f, 0.f, 0.f, 0.f);
            if (gn < Nn) v = *(const float4*)(B + (size_t)gn * ldb + k0 + lq * 4);
            Bs[lq * 4 + 0][r] = v.x; Bs[lq * 4 + 1][r] = v.y;
            Bs[lq * 4 + 2][r] = v.z; Bs[lq * 4 + 3][r] = v.w;
        }
        __syncthreads();

#pragma unroll
        for (int kk = 0; kk < BK; kk++) {
            float a[8], b[8];
            *(float4*)&a[0] = *(const float4*)&As[kk][ty * 4];
            *(float4*)&a[4] = *(const float4*)&As[kk][64 + ty * 4];
            *(float4*)&b[0] = *(const float4*)&Bs[kk][tx * 4];
            *(float4*)&b[4] = *(const float4*)&Bs[kk][64 + tx * 4];
#pragma unroll
            for (int i = 0; i < 8; i++)
#pragma unroll
                for (int j = 0; j < 8; j++) acc[i][j] += a[i] * b[j];
        }
        __syncthreads();
    }

    int row[8];
#pragma unroll
    for (int i = 0; i < 8; i++) row[i] = m0 + ((i < 4) ? (ty * 4 + i) : (64 + ty * 4 + (i - 4)));
    const int c0 = n0 + tx * 4;
    const int c1 = n0 + 64 + tx * 4;

    if (MODE == 0) {
#pragma unroll
        for (int i = 0; i < 8; i++) {
            if (row[i] >= M) continue;
            float* cp = C + (size_t)row[i] * ldc;
#pragma unroll
            for (int jh = 0; jh < 2; jh++) {
                int cc = jh ? c1 : c0;
                if (cc + 3 < Nn) {
                    *(float4*)(cp + cc) = make_float4(acc[i][jh * 4 + 0], acc[i][jh * 4 + 1],
                                                      acc[i][jh * 4 + 2], acc[i][jh * 4 + 3]);
                } else {
                    for (int j = 0; j < 4; j++)
                        if (cc + j < Nn) cp[cc + j] = acc[i][jh * 4 + j];
                }
            }
        }
    } else {
        float bv0[4], bv1[4];
#pragma unroll
        for (int j = 0; j < 4; j++) {
            bv0[j] = (c0 + j < Nn) ? bias[c0 + j] : 0.f;
            bv1[j] = (c1 + j < Nn) ? bias[c1 + j] : 0.f;
        }
#pragma unroll
        for (int i = 0; i < 8; i++) {
            int m = row[i];
            int t = m >> 6;
            int nb = m & 63;
            float* cp = C + ((size_t)nb * LL + t) * VOC;
#pragma unroll
            for (int jh = 0; jh < 2; jh++) {
                int cc = jh ? c1 : c0;
                float* bv = jh ? bv1 : bv0;
                if (cc + 3 < Nn) {
                    *(float4*)(cp + cc) = make_float4(acc[i][jh * 4 + 0] + bv[0],
                                                      acc[i][jh * 4 + 1] + bv[1],
                                                      acc[i][jh * 4 + 2] + bv[2],
                                                      acc[i][jh * 4 + 3] + bv[3]);
                } else {
                    for (int j = 0; j < 4; j++)
                        if (cc + j < Nn) cp[cc + j] = acc[i][jh * 4 + j] + bv[j];
                }
            }
        }
    }
}

// ---------------------------------------------------------------------------
// 64-block group barrier (sense-reversing generation counter).
// All communication stays within a super-group of 64 blocks / 16 batch rows.
// ---------------------------------------------------------------------------
__device__ __forceinline__ void group_sync(unsigned* cntp, unsigned* genp)
{
    __threadfence();           // release: my stores -> device visible
    __syncthreads();           // all threads of block fenced before arrival
    if (threadIdx.x == 0) {
        unsigned g = __hip_atomic_load(genp, __ATOMIC_RELAXED, __HIP_MEMORY_SCOPE_AGENT);
        unsigned old = __hip_atomic_fetch_add(cntp, 1u, __ATOMIC_RELAXED, __HIP_MEMORY_SCOPE_AGENT);
        if (old == GBLK - 1) {
            __hip_atomic_store(cntp, 0u, __ATOMIC_RELAXED, __HIP_MEMORY_SCOPE_AGENT);
            __hip_atomic_store(genp, g + 1u, __ATOMIC_RELEASE, __HIP_MEMORY_SCOPE_AGENT);
        } else {
            unsigned cur;
            do {
                __builtin_amdgcn_s_sleep(2);
                cur = __hip_atomic_load(genp, __ATOMIC_RELAXED, __HIP_MEMORY_SCOPE_AGENT);
            } while (cur == g);
        }
    }
    __syncthreads();
    __threadfence();           // acquire: subsequent loads see fresh data
}

// ---------------------------------------------------------------------------
// Cooperative sequential decoder.
// 256 blocks = 4 super-groups (g = b>>6) of 64 blocks <-> 16 batch rows each.
// Per block roles:
//   P1/P2 (gates): n-range [g*16, g*16+16), cell tile ct = b&63 (4 cells).
//                  Weight slices (16 gate rows each) persistent in LDS.
//   P3a (attention): row na = g*16 + ((b>>2)&15), time-quarter q = b&3.
//                  Flash-style partial softmax; last arriving block combines.
// 3 group barriers per step.
// ---------------------------------------------------------------------------
__global__ __launch_bounds__(256, 1)
void seq_coop(const float* __restrict__ Vmat,   // values [NB][TT][VS]
              const float* __restrict__ Kmat,   // key    [NB][TT][KS]
              const int* __restrict__ lens,
              const int* __restrict__ text,     // [NB][LL]
              const float* __restrict__ preE,   // [VOC][GATES]
              const float* __restrict__ W1c,    // [GATES][512]
              const float* __restrict__ W2c,    // [GATES][512]
              const float* __restrict__ b1s,    // [GATES]
              const float* __restrict__ b2s,    // [GATES]
              float* __restrict__ S,            // [LL][NB][HID]
              float* __restrict__ h1buf,        // [2][NB][256] ping-pong
              float* __restrict__ ctxbuf,       // [NB][256]
              float* __restrict__ am,           // [NB][4] partial max
              float* __restrict__ as_,          // [NB][4] partial sum
              float* __restrict__ actxp,        // [NB][4][256] partial ctx
              unsigned* __restrict__ cnt,       // [NB*16] padded arrival counters
              unsigned* __restrict__ bars)      // [4][64] barrier {count, gen}
{
    __shared__ float ws1[16][516];   // W1 slice (pad 516 -> rows 4 banks apart)
    __shared__ float ws2[16][516];   // W2 slice
    __shared__ float xs [16][516];   // x = 16 rows x 512
    __shared__ float gl [16][16];    // gate exchange
    __shared__ float red[256];
    __shared__ float h2s[256];
    __shared__ float pl [128];
    __shared__ float cred[4][64][4];
    __shared__ int   flagv;

    const int b   = blockIdx.x;
    const int tid = threadIdx.x;
    const int grp = b >> 6;
    const int n0  = grp * 16;
    const int ct  = b & 63;
    const int na  = n0 + ((b >> 2) & 15);
    const int q   = b & 3;
    const int t0a = q * 128;
    unsigned* cntp = bars + grp * 64;
    unsigned* genp = bars + grp * 64 + 32;

    const int sub = tid & 15;        // gate-output lane within tile
    const int nl  = tid >> 4;        // local batch row
    const int g4  = sub >> 2;        // gate type i/f/g/o
    const int cl  = sub & 3;         // cell within tile
    const int jj  = g4 * 256 + ct * 4 + cl;   // global gate row

    // ---- persistent weight slices -> LDS (once; reused for 256 steps) ----
    for (int i = tid; i < 2048; i += 256) {
        int r = i >> 7, k4 = i & 127;
        int j = (r >> 2) * 256 + ct * 4 + (r & 3);
        *(float4*)&ws1[r][k4 * 4] = *(const float4*)(W1c + (size_t)j * 512 + k4 * 4);
        *(float4*)&ws2[r][k4 * 4] = *(const float4*)(W2c + (size_t)j * 512 + k4 * 4);
    }
    const float b1r = b1s[jj];
    const float b2r = b2s[jj];
    const int len_att = lens[na];
    float c1reg = 0.f, c2reg = 0.f;

    // t = -1: initial attention only (h2 = 0) -> ctx_init. Then 256 steps.
    for (int t = -1; t < LL; ++t) {
        if (t >= 0) {
            const int p = t & 1;
            // ------------------- P1: gates1 + (h1,c1) -------------------
            for (int i = tid; i < 2048; i += 256) {
                int inl = i >> 7, k4 = i & 127;
                int n = n0 + inl;
                float4 v;
                if (k4 < 64)      v = *(const float4*)(ctxbuf + n * 256 + k4 * 4);
                else if (t == 0)  v = make_float4(0.f, 0.f, 0.f, 0.f);
                else              v = *(const float4*)(h1buf + (p ^ 1) * NB * 256 + n * 256 + (k4 - 64) * 4);
                *(float4*)&xs[inl][k4 * 4] = v;
            }
            __syncthreads();
            {
                int n = n0 + nl;
                int tok = (t == 0) ? SOSTOK : text[n * LL + (t - 1)];
                float pre = preE[(size_t)tok * GATES + jj];
                float4 a4 = make_float4(0.f, 0.f, 0.f, 0.f);
                const float* wr = &ws1[sub][0];
                const float* xr = &xs[nl][0];
#pragma unroll 8
                for (int k4 = 0; k4 < 128; k4++) {
                    float4 w  = *(const float4*)(wr + k4 * 4);
                    float4 xv = *(const float4*)(xr + k4 * 4);
                    a4.x += w.x * xv.x; a4.y += w.y * xv.y;
                    a4.z += w.z * xv.z; a4.w += w.w * xv.w;
                }
                gl[nl][sub] = (a4.x + a4.y) + (a4.z + a4.w) + b1r + pre;
            }
            __syncthreads();
            if (tid < 64) {
                int unl = tid >> 2, ucl = tid & 3;
                float gi = gl[unl][ucl],     gf = gl[unl][4 + ucl];
                float gg = gl[unl][8 + ucl], go = gl[unl][12 + ucl];
                float c = sigmoidf_(gf) * c1reg + sigmoidf_(gi) * tanhf(gg);
                float h = sigmoidf_(go) * tanhf(c);
                c1reg = c;
                h1buf[p * NB * 256 + (n0 + unl) * 256 + (ct * 4 + ucl)] = h;
            }
            group_sync(cntp, genp);

            // ------------------- P2: gates2 + (h2,c2) -------------------
            for (int i = tid; i < 2048; i += 256) {
                int inl = i >> 7, k4 = i & 127;
                int n = n0 + inl;
                float4 v;
                if (k4 < 64)      v = *(const float4*)(h1buf + p * NB * 256 + n * 256 + k4 * 4);
                else if (t == 0)  v = make_float4(0.f, 0.f, 0.f, 0.f);
                else              v = *(const float4*)(S + ((size_t)(t - 1) * NB + n) * HID + (k4 - 64) * 4);
                *(float4*)&xs[inl][k4 * 4] = v;
            }
            __syncthreads();
            {
                float4 a4 = make_float4(0.f, 0.f, 0.f, 0.f);
                const float* wr = &ws2[sub][0];
                const float* xr = &xs[nl][0];
#pragma unroll 8
                for (int k4 = 0; k4 < 128; k4++) {
                    float4 w  = *(const float4*)(wr + k4 * 4);
                    float4 xv = *(const float4*)(xr + k4 * 4);
                    a4.x += w.x * xv.x; a4.y += w.y * xv.y;
                    a4.z += w.z * xv.z; a4.w += w.w * xv.w;
                }
                gl[nl][sub] = (a4.x + a4.y) + (a4.z + a4.w) + b2r;
            }
            __syncthreads();
            if (tid < 64) {
                int unl = tid >> 2, ucl = tid & 3;
                float gi = gl[unl][ucl],     gf = gl[unl][4 + ucl];
                float gg = gl[unl][8 + ucl], go = gl[unl][12 + ucl];
                float c = sigmoidf_(gf) * c2reg + sigmoidf_(gi) * tanhf(gg);
                float h = sigmoidf_(go) * tanhf(c);
                c2reg = c;
                S[((size_t)t * NB + (n0 + unl)) * HID + (ct * 4 + ucl)] = h;
            }
            group_sync(cntp, genp);
        }

        // ------------------- P3a: attention (quarter q of row na) -------------------
        h2s[tid] = (t < 0) ? 0.f : S[((size_t)t * NB + na) * HID + tid];
        __syncthreads();
        {
            int tl = tid >> 1, kh = tid & 1;
            int tg = t0a + tl;
            float e = 0.f;
            if (tg < len_att) {
                const float4* kr = (const float4*)(Kmat + ((size_t)na * TT + tg) * KS) + kh * 32;
                const float4* hh = ((const float4*)h2s) + kh * 32;
#pragma unroll 8
                for (int k4 = 0; k4 < 32; k4++) {
                    float4 kv = kr[k4], hv = hh[k4];
                    e += kv.x * hv.x + kv.y * hv.y + kv.z * hv.z + kv.w * hv.w;
                }
            }
            red[tid] = e;
        }
        __syncthreads();
        if (tid < 128) {
            int tg = t0a + tid;
            float ef = (tg < len_att) ? (red[2 * tid] + red[2 * tid + 1]) : -1e30f;
            pl[tid] = ef;
        }
        __syncthreads();
        red[tid] = (tid < 128) ? pl[tid] : -1e30f;
        __syncthreads();
        for (int s = 128; s > 0; s >>= 1) {
            if (tid < s) red[tid] = fmaxf(red[tid], red[tid + s]);
            __syncthreads();
        }
        float mq = red[0];
        __syncthreads();
        {
            float pv = 0.f;
            if (tid < 128 && (t0a + tid) < len_att) pv = expf(pl[tid] - mq);
            if (tid < 128) pl[tid] = pv;
            red[tid] = pv;
        }
        __syncthreads();
        for (int s = 128; s > 0; s >>= 1) {
            if (tid < s) red[tid] += red[tid + s];
            __syncthreads();
        }
        float sq = red[0];
        __syncthreads();
        {
            int tq = tid >> 6, v4 = tid & 63;
            float4 a = make_float4(0.f, 0.f, 0.f, 0.f);
            int tlim = len_att - t0a;                   // valid tl < tlim
            int tend = min(tq * 32 + 32, tlim);
            for (int tl = tq * 32; tl < tend; tl++) {
                float p_ = pl[tl];
                float4 vv = *(const float4*)(Vmat + ((size_t)na * TT + t0a + tl) * VS + v4 * 4);
                a.x += p_ * vv.x; a.y += p_ * vv.y; a.z += p_ * vv.z; a.w += p_ * vv.w;
            }
            cred[tq][v4][0] = a.x; cred[tq][v4][1] = a.y;
            cred[tq][v4][2] = a.z; cred[tq][v4][3] = a.w;
        }
        __syncthreads();
        {
            int v4 = tid >> 2, comp = tid & 3;
            float sum = cred[0][v4][comp] + cred[1][v4][comp]
                      + cred[2][v4][comp] + cred[3][v4][comp];
            actxp[(size_t)(na * 4 + q) * 256 + tid] = sum;
        }
        if (tid == 0) { am[na * 4 + q] = mq; as_[na * 4 + q] = sq; }
        __threadfence();
        __syncthreads();
        if (tid == 0) {
            unsigned old = __hip_atomic_fetch_add(&cnt[na * 16], 1u,
                                                  __ATOMIC_RELAXED, __HIP_MEMORY_SCOPE_AGENT);
            flagv = (old == 3u) ? 1 : 0;
        }
        __syncthreads();
        if (flagv) {                 // last arriving block of row na: combine
            __threadfence();
            float m0 = am[na * 4 + 0], m1 = am[na * 4 + 1];
            float m2 = am[na * 4 + 2], m3 = am[na * 4 + 3];
            float M = fmaxf(fmaxf(m0, m1), fmaxf(m2, m3));
            float w0 = expf(m0 - M), w1 = expf(m1 - M);
            float w2 = expf(m2 - M), w3 = expf(m3 - M);
            float denom = as_[na * 4 + 0] * w0 + as_[na * 4 + 1] * w1
                        + as_[na * 4 + 2] * w2 + as_[na * 4 + 3] * w3;
            float inv = 1.0f / denom;
            float cv = (actxp[(size_t)(na * 4 + 0) * 256 + tid] * w0
                      + actxp[(size_t)(na * 4 + 1) * 256 + tid] * w1
                      + actxp[(size_t)(na * 4 + 2) * 256 + tid] * w2
                      + actxp[(size_t)(na * 4 + 3) * 256 + tid] * w3) * inv;
            ctxbuf[na * 256 + tid] = cv;
            if (t >= 0) S[((size_t)t * NB + na) * HID + 256 + tid] = cv;
            if (tid == 0)
                __hip_atomic_store(&cnt[na * 16], 0u, __ATOMIC_RELAXED, __HIP_MEMORY_SCOPE_AGENT);
        }
        group_sync(cntp, genp);
    }
}

// ---------------------------------------------------------------------------
extern "C" void kernel_launch(void* const* d_in, const int* in_sizes, int n_in,
                              void* d_out, int out_size, void* d_ws, size_t ws_size,
                              hipStream_t stream)
{
    const float* values = (const float*)d_in[0];
    const float* key    = (const float*)d_in[1];
    const int*   lens   = (const int*)d_in[2];
    const int*   text   = (const int*)d_in[3];
    const float* E      = (const float*)d_in[4];
    const float* b_out  = (const float*)d_in[5];
    const float* W_ih1  = (const float*)d_in[6];
    const float* W_hh1  = (const float*)d_in[7];
    const float* b_ih1  = (const float*)d_in[8];
    const float* b_hh1  = (const float*)d_in[9];
    const float* W_ih2  = (const float*)d_in[10];
    const float* W_hh2  = (const float*)d_in[11];
    const float* b_ih2  = (const float*)d_in[12];
    const float* b_hh2  = (const float*)d_in[13];

    float* ws     = (float*)d_ws;
    float* W1c    = ws;                       // 1024*512          = 524288
    float* W2c    = W1c + 524288;             // 524288
    float* b1s    = W2c + 524288;             // 1024
    float* b2s    = b1s + 1024;               // 1024
    float* preE   = b2s + 1024;               // 10000*1024        = 10240000
    float* S      = preE + 10240000;          // 256*64*512        = 8388608
    float* h1buf  = S + 8388608;              // 2*64*256          = 32768
    float* ctxbuf = h1buf + 32768;            // 64*256            = 16384
    float* am     = ctxbuf + 16384;           // 256
    float* as_    = am + 256;                 // 256
    float* actxp  = as_ + 256;                // 64*4*256          = 65536
    unsigned* cnt  = (unsigned*)(actxp + 65536);  // 1024 u32 (padded counters)
    unsigned* bars = cnt + 1024;                  // 256 u32 (4 groups x {count,gen})
    float* out    = (float*)d_out;            // [64][256][10000]

    // 1) pack row-contiguous weights + bias sums; zero sync state
    hipLaunchKernelGGL(pack_kernel, dim3(2048), dim3(256), 0, stream,
                       W_ih1, W_hh1, b_ih1, b_hh1, W_ih2, W_hh2, b_ih2, b_hh2,
                       W1c, W2c, b1s, b2s, cnt, bars);

    // 2) preE[v][j] = sum_{k<512} E[v][k] * W_ih1[j][k]   (embedding part of gates1)
    hipLaunchKernelGGL((gemm_nt<0>), dim3(8, 79), dim3(256), 0, stream,
                       E, W_ih1, preE, (const float*)nullptr,
                       10000, 1024, 512, 512, 768, 1024);

    // 3) cooperative sequential decoder: 256 blocks (all CUs)
    void* args[] = {(void*)&values, (void*)&key, (void*)&lens, (void*)&text,
                    (void*)&preE, (void*)&W1c, (void*)&W2c, (void*)&b1s, (void*)&b2s,
                    (void*)&S, (void*)&h1buf, (void*)&ctxbuf, (void*)&am, (void*)&as_,
                    (void*)&actxp, (void*)&cnt, (void*)&bars};
    hipLaunchCooperativeKernel((void*)seq_coop, dim3(NBLK), dim3(NTHR), args, 0, stream);

    // 4) logits: out[n][t][v] = S[t][n][:] . E[v][:] + b_out[v]
    hipLaunchKernelGGL((gemm_nt<1>), dim3(79, 128), dim3(256), 0, stream,
                       S, E, out, b_out,
                       16384, 10000, 512, 512, 512, 0);
}